// Round 10
// baseline (303.810 us; speedup 1.0000x reference)
//
#include <hip/hip_runtime.h>
#include <hip/hip_bf16.h>

#define NN 2048
#define BB 8
#define FD 256
#define NEG_SLOPE 0.2f
#define EPSV 1e-7f
#define PSTR 36   // padded P row stride (bf16)

typedef __bf16 bf16x8 __attribute__((ext_vector_type(8)));
typedef __bf16 bf16x4 __attribute__((ext_vector_type(4)));
typedef float f32x4 __attribute__((ext_vector_type(4)));

// async 16B global -> LDS (lds base wave-uniform; dest = base + lane*16)
__device__ __forceinline__ void gload16(const __bf16* g, __bf16* l) {
    __builtin_amdgcn_global_load_lds((const __attribute__((address_space(1))) unsigned int*)g,
                                     (__attribute__((address_space(3))) unsigned int*)l,
                                     16, 0, 0);
}

// ---------------- K1: WT[o][f] = bf16(W[f][o]) ----------------
__global__ __launch_bounds__(256) void k1_prep(const float* __restrict__ W,
                                               __bf16* __restrict__ WT) {
    int idx = blockIdx.x * 256 + threadIdx.x;   // 256 blocks
    int o = idx >> 8, f = idx & 255;
    WT[idx] = (__bf16)W[f * FD + o];
}

// ---------------- K2: Wh = x @ W (bf16 MFMA) + fused s_src/s_dst scores --------
__global__ __launch_bounds__(256) void k2_whgemm(const float* __restrict__ x,
                                                 const __bf16* __restrict__ WT,
                                                 const float* __restrict__ a_w,
                                                 float* __restrict__ Wh,
                                                 float* __restrict__ s_src,
                                                 float* __restrict__ s_dst) {
    const int wave = threadIdx.x >> 6;
    const int lane = threadIdx.x & 63;
    const int row0 = blockIdx.x * 32 + (wave >> 1) * 16;
    const int ohalf = (wave & 1) * 128;
    const int m = lane & 15;
    const int quad = lane >> 4;
    const int row = row0 + m;
    const float* xrow = x + (size_t)row * FD + quad * 8;

    f32x4 acc[8];
#pragma unroll
    for (int n = 0; n < 8; ++n) acc[n] = (f32x4){0.f, 0.f, 0.f, 0.f};

    for (int k0 = 0; k0 < FD; k0 += 32) {
        float4 xa = *(const float4*)(xrow + k0);
        float4 xb = *(const float4*)(xrow + k0 + 4);
        bf16x8 af;
        af[0] = (__bf16)xa.x; af[1] = (__bf16)xa.y; af[2] = (__bf16)xa.z; af[3] = (__bf16)xa.w;
        af[4] = (__bf16)xb.x; af[5] = (__bf16)xb.y; af[6] = (__bf16)xb.z; af[7] = (__bf16)xb.w;
#pragma unroll
        for (int n = 0; n < 8; ++n) {
            int o = ohalf + n * 16 + m;
            bf16x8 bf = *(const bf16x8*)(WT + o * FD + k0 + quad * 8);
            acc[n] = __builtin_amdgcn_mfma_f32_16x16x32_bf16(af, bf, acc[n], 0, 0, 0);
        }
    }
#pragma unroll
    for (int n = 0; n < 8; ++n) {
        int o = ohalf + n * 16 + m;
#pragma unroll
        for (int r = 0; r < 4; ++r) {
            Wh[(size_t)(row0 + quad * 4 + r) * FD + o] = acc[n][r];
        }
    }

    float psrc[4] = {0.f, 0.f, 0.f, 0.f};
    float pdst[4] = {0.f, 0.f, 0.f, 0.f};
#pragma unroll
    for (int n = 0; n < 8; ++n) {
        int o = ohalf + n * 16 + m;
        float awS = a_w[o], awD = a_w[FD + o];
#pragma unroll
        for (int r = 0; r < 4; ++r) {
            psrc[r] += acc[n][r] * awS;
            pdst[r] += acc[n][r] * awD;
        }
    }
#pragma unroll
    for (int off = 1; off <= 8; off <<= 1) {
#pragma unroll
        for (int r = 0; r < 4; ++r) {
            psrc[r] += __shfl_xor(psrc[r], off, 64);
            pdst[r] += __shfl_xor(pdst[r], off, 64);
        }
    }
    __shared__ float sS[2][2][16], sD[2][2][16];
    if (m == 0) {
        int rp = wave >> 1, oh = wave & 1;
#pragma unroll
        for (int r = 0; r < 4; ++r) {
            sS[rp][oh][quad * 4 + r] = psrc[r];
            sD[rp][oh][quad * 4 + r] = pdst[r];
        }
    }
    __syncthreads();
    if (threadIdx.x < 32) {
        int rp = threadIdx.x >> 4, idx = threadIdx.x & 15;
        int orow = blockIdx.x * 32 + rp * 16 + idx;
        s_src[orow] = sS[rp][0][idx] + sS[rp][1][idx];
        s_dst[orow] = sD[rp][0][idx] + sD[rp][1][idx];
    }
}

// ---------------- K4: den_part partial sums + Apack (4 adjacency bits / byte) ----
// grid 1024: b = blk&7, jhalf = (blk>>3)&1, isp = blk>>4; 32 i x 1024 j per block
__global__ __launch_bounds__(256) void k4_den(const float* __restrict__ A,
                                              const float* __restrict__ s_src,
                                              const float* __restrict__ s_dst,
                                              const float* __restrict__ a_bp,
                                              float* __restrict__ den_part,
                                              unsigned char* __restrict__ Apack) {
    const int blk = blockIdx.x;
    const int b = blk & 7;
    const int jhalf = (blk >> 3) & 1;
    const int isp = blk >> 4;
    const int i0 = isp * 32;
    const int j = jhalf * 1024 + threadIdx.x * 4;
    __shared__ float ss[32];
    if (threadIdx.x < 32) ss[threadIdx.x] = s_src[b * NN + i0 + threadIdx.x] + a_bp[0];
    __syncthreads();
    float4 sd = *(const float4*)(s_dst + b * NN + j);
    float ax = 0.f, ay = 0.f, az = 0.f, aw = 0.f;
    const float* Ap = A + ((size_t)b * NN + i0) * NN + j;
    unsigned char* Pk = Apack + ((size_t)(b * NN + i0)) * 512 + jhalf * 256 + threadIdx.x;
#pragma unroll 8
    for (int i = 0; i < 32; ++i) {
        float4 a = *(const float4*)(Ap + (size_t)i * NN);
        float si = ss[i];
        float e0 = si + sd.x; e0 = e0 > 0.f ? e0 : NEG_SLOPE * e0;
        float e1 = si + sd.y; e1 = e1 > 0.f ? e1 : NEG_SLOPE * e1;
        float e2 = si + sd.z; e2 = e2 > 0.f ? e2 : NEG_SLOPE * e2;
        float e3 = si + sd.w; e3 = e3 > 0.f ? e3 : NEG_SLOPE * e3;
        ax += a.x * __expf(e0);
        ay += a.y * __expf(e1);
        az += a.z * __expf(e2);
        aw += a.w * __expf(e3);
        unsigned nib = (a.x > 0.5f ? 1u : 0u) | (a.y > 0.5f ? 2u : 0u) |
                       (a.z > 0.5f ? 4u : 0u) | (a.w > 0.5f ? 8u : 0u);
        Pk[(size_t)i * 512] = (unsigned char)nib;
    }
    float4 r = (float4){ax, ay, az, aw};
    *(float4*)(den_part + (size_t)isp * (BB * NN) + b * NN + j) = r;
}

// ---------------- K5: WhT[b][o][j] = bf16( Wh[b][j][o] / (sum(den_part)+eps) ) ----
__global__ __launch_bounds__(256) void k5_wht(const float* __restrict__ Wh,
                                              const float* __restrict__ den_part,
                                              __bf16* __restrict__ WhT) {
    const int b = blockIdx.z;
    const int j0 = blockIdx.x * 64;
    const int o0 = blockIdx.y * 64;
    __shared__ float tile[64][65];
    __shared__ float invd[64];
    if (threadIdx.x < 64) {
        float s = 0.f;
        const float* dp = den_part + b * NN + j0 + threadIdx.x;
#pragma unroll 8
        for (int sI = 0; sI < 64; ++sI) s += dp[(size_t)sI * (BB * NN)];
        invd[threadIdx.x] = 1.f / (s + EPSV);
    }
    __syncthreads();
    int jr = threadIdx.x >> 4, oc = (threadIdx.x & 15) * 4;
#pragma unroll
    for (int p = 0; p < 4; ++p) {
        int jj = jr + p * 16;
        float4 v = *(const float4*)(Wh + (size_t)(b * NN + j0 + jj) * FD + o0 + oc);
        float s = invd[jj];
        tile[jj][oc + 0] = v.x * s;
        tile[jj][oc + 1] = v.y * s;
        tile[jj][oc + 2] = v.z * s;
        tile[jj][oc + 3] = v.w * s;
    }
    __syncthreads();
    int ow = threadIdx.x >> 4, jc = (threadIdx.x & 15) * 4;
#pragma unroll
    for (int p = 0; p < 4; ++p) {
        int o = ow + p * 16;
        bf16x4 wv;
        wv[0] = (__bf16)tile[jc + 0][o];
        wv[1] = (__bf16)tile[jc + 1][o];
        wv[2] = (__bf16)tile[jc + 2][o];
        wv[3] = (__bf16)tile[jc + 3][o];
        *(bf16x4*)(WhT + (size_t)(b * FD + o0 + o) * NN + j0 + jc) = wv;
    }
}

// ---------------- K6: fused full-K GEMM from packed adjacency ---------------------
// out = (A*exp(lrelu(e))) @ WhT^T. grid 1024: b = blk&7, r_ = blk>>3: itile = r_&63,
// oh = r_>>6. Block = 32i x 128o, 256 thr = 4 waves (2 wrow x 2 wcol).
// A never re-read: P rebuilt from Apack (1 byte / 4 j, L1/L2-resident) + s_dst.
__global__ __launch_bounds__(256) void k6_out(const unsigned char* __restrict__ Apack,
                                              const __bf16* __restrict__ WhT,
                                              const float* __restrict__ s_src,
                                              const float* __restrict__ s_dst,
                                              const float* __restrict__ a_bp,
                                              float* __restrict__ out) {
    __shared__ __bf16 Pt[2][32 * PSTR];   // 2 x 2304 B
    __shared__ __bf16 Bt[2][128 * 32];    // 2 x 8 KiB
    const int blk = blockIdx.x;
    const int b = blk & 7;
    const int r_ = blk >> 3;
    const int itile = r_ & 63;
    const int oh = r_ >> 6;
    const int i0 = itile * 32;
    const int o0 = oh * 128;
    const int t = threadIdx.x;
    const int w = t >> 6, lane = t & 63;
    const int m = lane & 15, quad = lane >> 4;
    const int wrow = w >> 1, wcol = w & 1;

    // P-build role: thread t -> row t>>3 (0..31), cols (t&7)*4 .. +3
    const int prow = t >> 3, pjq = t & 7;
    const float ssr = s_src[b * NN + i0 + prow] + a_bp[0];
    const unsigned char* Apb = Apack + ((size_t)(b * NN + i0 + prow)) * 512 + pjq;
    const float* sdbase = s_dst + b * NN + pjq * 4;
    __bf16* Pw = &Pt[0][0] + prow * PSTR + pjq * 4;
    const int pstep = 32 * PSTR;

    // B staging: wave w stages rows [w*16,+16) and [w*16+64,+16); lane -> row +(l>>2),
    // chunk l&3. 128 rows x 32 K per step.
    const __bf16* gB0 = WhT + ((size_t)(b * FD + o0 + w * 16 + (lane >> 2))) * NN + (lane & 3) * 8;
    const __bf16* gB1 = gB0 + (size_t)64 * NN;
    __bf16* lB0 = &Bt[0][0] + (w * 16) * 32;        // wave-uniform
    __bf16* lB1 = &Bt[0][0] + (w * 16 + 64) * 32;
    const int lstepB = 128 * 32;

    // prefetch step-0 operands
    unsigned ab = Apb[0];
    float4 q0 = *(const float4*)(sdbase);
    gload16(gB0, lB0);
    gload16(gB1, lB1);

#define BUILD_P(dstbuf)                                                          \
    {                                                                            \
        bf16x4 pv; float e;                                                      \
        e = ssr + q0.x; e = e > 0.f ? e : NEG_SLOPE * e;                         \
        pv[0] = (__bf16)((ab & 1u) ? __expf(e) : 0.f);                           \
        e = ssr + q0.y; e = e > 0.f ? e : NEG_SLOPE * e;                         \
        pv[1] = (__bf16)((ab & 2u) ? __expf(e) : 0.f);                           \
        e = ssr + q0.z; e = e > 0.f ? e : NEG_SLOPE * e;                         \
        pv[2] = (__bf16)((ab & 4u) ? __expf(e) : 0.f);                           \
        e = ssr + q0.w; e = e > 0.f ? e : NEG_SLOPE * e;                         \
        pv[3] = (__bf16)((ab & 8u) ? __expf(e) : 0.f);                           \
        *(bf16x4*)(Pw + (dstbuf) * pstep) = pv;                                  \
    }

    BUILD_P(0)

    f32x4 acc[4];
#pragma unroll
    for (int n = 0; n < 4; ++n) acc[n] = (f32x4){0.f, 0.f, 0.f, 0.f};

    const __bf16* Pr = &Pt[0][0] + (wrow * 16 + m) * PSTR + quad * 8;
    const __bf16* Br = &Bt[0][0] + (wcol * 64 + m) * 32 + quad * 8;

    for (int kk = 0; kk < 64; ++kk) {
        __syncthreads();   // buf (kk&1) fully staged
        const int cur = kk & 1, nb = cur ^ 1;
        if (kk < 63) {
            gload16(gB0 + (kk + 1) * 32, lB0 + nb * lstepB);
            gload16(gB1 + (kk + 1) * 32, lB1 + nb * lstepB);
            ab = Apb[(kk + 1) * 8];
            q0 = *(const float4*)(sdbase + (kk + 1) * 32);
        }
        const __bf16* Pk = Pr + cur * pstep;
        const __bf16* Bk = Br + cur * lstepB;
        bf16x8 af = *(const bf16x8*)(Pk);
#pragma unroll
        for (int n = 0; n < 4; ++n) {
            bf16x8 bfr = *(const bf16x8*)(Bk + n * 16 * 32);
            acc[n] = __builtin_amdgcn_mfma_f32_16x16x32_bf16(af, bfr, acc[n], 0, 0, 0);
        }
        if (kk < 63) BUILD_P(nb)
    }

#pragma unroll
    for (int n = 0; n < 4; ++n) {
        int o = o0 + wcol * 64 + n * 16 + m;
#pragma unroll
        for (int rr = 0; rr < 4; ++rr) {
            int orow = i0 + wrow * 16 + quad * 4 + rr;
            out[((size_t)b * NN + orow) * FD + o] = acc[n][rr];
        }
    }
#undef BUILD_P
}

extern "C" void kernel_launch(void* const* d_in, const int* in_sizes, int n_in,
                              void* d_out, int out_size, void* d_ws, size_t ws_size,
                              hipStream_t stream) {
    const float* A   = (const float*)d_in[0];
    const float* x   = (const float*)d_in[1];
    const float* W   = (const float*)d_in[2];
    const float* a_w = (const float*)d_in[3];
    const float* a_b = (const float*)d_in[4];
    float* out = (float*)d_out;

    char* ws = (char*)d_ws;
    __bf16* WT      = (__bf16*)ws;                      // 131,072 B
    float*  Wh      = (float*)(ws + 131072);            // 16,777,216 B
    __bf16* WhT     = (__bf16*)(ws + 16908288);         // 8,388,608 B
    float*  s_src   = (float*)(ws + 25296896);          // 65,536 B
    float*  s_dst   = (float*)(ws + 25362432);          // 65,536 B
    float*  den_part= (float*)(ws + 25427968);          // 64*16384*4 = 4,194,304 B
    unsigned char* Apack = (unsigned char*)(ws + 29622272); // 8*2048*512 = 8,388,608 B

    k1_prep<<<256, 256, 0, stream>>>(W, WT);
    k2_whgemm<<<512, 256, 0, stream>>>(x, WT, a_w, Wh, s_src, s_dst);
    k4_den<<<1024, 256, 0, stream>>>(A, s_src, s_dst, a_b, den_part, Apack);
    k5_wht<<<dim3(32, 4, 8), 256, 0, stream>>>(Wh, den_part, WhT);
    k6_out<<<1024, 256, 0, stream>>>(Apack, WhT, s_src, s_dst, a_b, out);
}